// Round 11
// baseline (1868.825 us; speedup 1.0000x reference)
//
#include <hip/hip_runtime.h>
#include <hip/hip_fp16.h>

#define T_SEQ   2048
#define HID     50
#define NPAD    256     // type-major: n = type*64 + u  (u<50 real, 4 gate types)
#define KPAD    64      // 50 h + 13 onehot + 1 bias
#define MB      4       // batch rows per block
#define NBLK    512     // 2048 / MB -> 2 blocks/CU
#define NTHR    256     // 4 waves
#define HSTR    80      // hA row stride in ushorts (160B)

typedef __attribute__((ext_vector_type(4))) float        f32x4;
typedef __attribute__((ext_vector_type(4))) unsigned int u32x4;  // raw 4-VGPR operand

__device__ __forceinline__ ushort f16b(float f) {
    return __half_as_ushort(__float2half(f));   // RNE
}
__device__ __forceinline__ float rcp_(float x) { return __builtin_amdgcn_rcpf(x); }
__device__ __forceinline__ float sigm(float x) { return rcp_(1.f + __expf(-x)); }
__device__ __forceinline__ float tanh_(float x) {
    return fmaf(2.f, rcp_(1.f + __expf(-2.f * x)), -1.f);
}

// B[n][k] f16 bits, n = type*64 + u (type 0..3 = i,f,g,o; u<50 real, else 0):
//  k in [0,50) : W_hh[g][k], g = type*50+u
//  k in [50,63): Ttab[v=k-50][g]   (x onehot)
//  k == 63     : b_ih[g]+b_hh[g]   (x 1)
__global__ void build_B(const float* __restrict__ embed,
                        const float* __restrict__ Wih,
                        const float* __restrict__ Whh,
                        const float* __restrict__ bih,
                        const float* __restrict__ bhh,
                        ushort* __restrict__ B) {
    int idx = blockIdx.x * blockDim.x + threadIdx.x;
    if (idx >= NPAD * KPAD) return;
    int n = idx >> 6, k = idx & 63;
    int type = n >> 6, u = n & 63;
    ushort v = 0;
    if (u < HID) {
        int g = type * HID + u;
        if (k < HID) {
            v = f16b(Whh[g * HID + k]);
        } else if (k < 63) {
            int vv = k - HID;
            float tt = 0.f;
            for (int e = 0; e < HID; ++e)
                tt = fmaf(embed[vv * HID + e], Wih[g * HID + e], tt);
            v = f16b(tt);
        } else {
            v = f16b(bih[g] + bhh[g]);
        }
    }
    B[idx] = v;
}

// 512 blocks x 256 threads (4 waves); block = batch rows [blockIdx.x*4, +4).
// Hand-asm MFMA with "v" constraints on ALL operands: forces arch-VGPR
// residency at every use site -> kills the v_accvgpr_read/write flood that
// builtins induce (allocator AGPR-homes builtin-only operands).
__global__ __launch_bounds__(NTHR, 2) void lstm_mfma(
    const int*    __restrict__ x,
    const ushort* __restrict__ Bmat,
    const float*  __restrict__ W1,
    const float*  __restrict__ b1,
    const float*  __restrict__ W2,
    const float*  __restrict__ b2,
    float*        __restrict__ out)
{
    const int t   = threadIdx.x;
    const int w   = t >> 6;
    const int l   = t & 63;
    const int c16 = l & 15;
    const int q   = l >> 4;

    __shared__ __align__(16) ushort hA[2][MB * HSTR];   // ping-pong A staging
    __shared__ float R1[MB][HID + 2];                   // epilogue scratch

    // wave w: types 0..3 of units u in [16w, 16w+16); 8 frags = 32 VGPRs
    u32x4 bf[4][2];
    #pragma unroll
    for (int ty = 0; ty < 4; ++ty)
        #pragma unroll
        for (int kf = 0; kf < 2; ++kf)
            bf[ty][kf] = *(const u32x4*)(Bmat + (ty * 64 + w * 16 + c16) * KPAD
                                              + kf * 32 + q * 8);

    for (int i = t; i < 2 * MB * HSTR; i += NTHR) ((ushort*)hA)[i] = 0;
    __syncthreads();

    const long xbase = (long)blockIdx.x * MB * T_SEQ;
    int tm1 = 0, t0 = 0, tp1 = 0;
    if (t < MB) {
        int k0 = x[xbase + (long)t * T_SEQ + 0];
        int k1 = x[xbase + (long)t * T_SEQ + 1];
        hA[0][t * HSTR + 63] = 0x3C00;          // bias slot = 1.0 (both bufs)
        hA[1][t * HSTR + 63] = 0x3C00;
        hA[0][t * HSTR + HID + k0] = 0x3C00;    // onehot for step 0
        tm1 = k0; t0 = k0; tp1 = k1;
    }
    float c[MB] = {0.f, 0.f, 0.f, 0.f};         // cell state rows 0..3 (q==0)
    __syncthreads();

    const int rsel = (c16 & 3) * HSTR + q * 8;  // A rows 4..15 wrap onto 0..3
    const int u    = w * 16 + c16;              // this lane's hidden unit

    for (int s = 0; s < T_SEQ; ++s) {
        const ushort* rb = hA[s & 1];
        ushort*       wb = hA[(s + 1) & 1];

        u32x4 a0 = *(const u32x4*)(rb + rsel);
        u32x4 a1 = *(const u32x4*)(rb + rsel + 32);

        f32x4 z[4];
        #pragma unroll
        for (int ty = 0; ty < 4; ++ty) { z[ty] = (f32x4){0.f, 0.f, 0.f, 0.f}; }

        // s_nop 1: 2 wait states for VALU(z-init mov) -> MFMA SrcC hazard.
        // Chained MFMA on same accumulator is 0-wait (pipelined).
        #pragma unroll
        for (int ty = 0; ty < 4; ++ty) {
            asm volatile("s_nop 1\n\t"
                         "v_mfma_f32_16x16x32_f16 %0, %1, %3, %0\n\t"
                         "v_mfma_f32_16x16x32_f16 %0, %2, %4, %0"
                         : "+v"(z[ty])
                         : "v"(a0), "v"(a1), "v"(bf[ty][0]), "v"(bf[ty][1]));
        }
        // 12 wait states: MFMA write D -> VALU read hazard, with data deps so
        // the activation reads cannot be scheduled before it.
        asm volatile("s_nop 7\n\t"
                     "s_nop 3"
                     : "+v"(z[0]), "+v"(z[1]), "+v"(z[2]), "+v"(z[3]));

        if (q == 0) {   // rows 0..3 real; activation fully lane-local
            #pragma unroll
            for (int r = 0; r < MB; ++r) {
                float iv = sigm(z[0][r]);
                float fv = sigm(z[1][r]);
                float gv = tanh_(z[2][r]);
                float ov = sigm(z[3][r]);
                c[r] = fv * c[r] + iv * gv;
                float h = ov * tanh_(c[r]);
                if (u < HID)
                    wb[r * HSTR + u] = f16b(h);
            }
        }
        if (t < MB) {
            wb[t * HSTR + HID + tm1] = 0;                         // clear x[s-1]
            if (s + 1 < T_SEQ) wb[t * HSTR + HID + tp1] = 0x3C00; // set x[s+1]
            tm1 = t0; t0 = tp1;
            if (s + 2 < T_SEQ) tp1 = x[xbase + (long)t * T_SEQ + s + 2];
        }
        __syncthreads();   // single barrier: wb complete before it becomes rb
    }

    // Epilogue MLP: final h is in hA[0] (T_SEQ even)
    const ushort* hf = hA[0];
    if (t < MB * HID) {                // 200 threads, one (m,u) each
        int uu = t % HID;
        int m  = t / HID;
        float a = b1[uu];
        #pragma unroll 10
        for (int k = 0; k < HID; ++k)
            a = fmaf(W1[uu * HID + k],
                     __half2float(__ushort_as_half(hf[m * HSTR + k])), a);
        R1[m][uu] = fmaxf(a, 0.f);
    }
    __syncthreads();
    if (t < MB) {
        float a = b2[0];
        #pragma unroll 10
        for (int j = 0; j < HID; ++j)
            a = fmaf(W2[j], R1[t][j], a);
        out[blockIdx.x * MB + t] = a;
    }
}

extern "C" void kernel_launch(void* const* d_in, const int* in_sizes, int n_in,
                              void* d_out, int out_size, void* d_ws, size_t ws_size,
                              hipStream_t stream) {
    const int*   x     = (const int*)  d_in[0];
    const float* embed = (const float*)d_in[1];
    const float* W_ih  = (const float*)d_in[2];
    const float* W_hh  = (const float*)d_in[3];
    const float* b_ih  = (const float*)d_in[4];
    const float* b_hh  = (const float*)d_in[5];
    const float* W1    = (const float*)d_in[6];
    const float* b1    = (const float*)d_in[7];
    const float* W2    = (const float*)d_in[8];
    const float* b2    = (const float*)d_in[9];
    float* out = (float*)d_out;

    ushort* Bmat = (ushort*)d_ws;  // NPAD*KPAD*2 = 32,768 B scratch

    build_B<<<(NPAD * KPAD + 255) / 256, 256, 0, stream>>>(
        embed, W_ih, W_hh, b_ih, b_hh, Bmat);

    lstm_mfma<<<NBLK, NTHR, 0, stream>>>(
        x, Bmat, W1, b1, W2, b2, out);
}

// Round 12
// 1428.364 us; speedup vs baseline: 1.3084x; 1.3084x over previous
//
#include <hip/hip_runtime.h>
#include <hip/hip_fp16.h>

#define T_SEQ   2048
#define HID     50
#define UPAD    64      // unit padding (type-major: n = ty*64 + u)
#define NPAD    256     // 4 types * 64
#define KPAD    64      // h padded 50 -> 64 (K = 2 MFMAs of 32)
#define NBLK    2048    // one wave (block of 64) per batch element
#define VOC     13

typedef __attribute__((ext_vector_type(8))) _Float16 half8;
typedef __attribute__((ext_vector_type(4))) float    f32x4;

__device__ __forceinline__ ushort f16b(float f) {
    return __half_as_ushort(__float2half(f));   // RNE
}
__device__ __forceinline__ float h2f(ushort h) {
    return __half2float(__ushort_as_half(h));
}
__device__ __forceinline__ float rcp_(float x) { return __builtin_amdgcn_rcpf(x); }
__device__ __forceinline__ float sigm(float x) { return rcp_(1.f + __expf(-x)); }
__device__ __forceinline__ float tanh_(float x) {
    return fmaf(2.f, rcp_(1.f + __expf(-2.f * x)), -1.f);
}

// Bmat[n][k], n = ty*64+u: W_hh[ty*50+u][k] (u<50, k<50), else 0.  f16 bits.
__global__ void build_B(const float* __restrict__ Whh, ushort* __restrict__ B) {
    int idx = blockIdx.x * blockDim.x + threadIdx.x;
    if (idx >= NPAD * KPAD) return;
    int n = idx >> 6, k = idx & 63;
    int ty = n >> 6, u = n & 63;
    B[idx] = (u < HID && k < HID) ? f16b(Whh[(ty * HID + u) * HID + k]) : (ushort)0;
}

// Tt[v][u] = ushort4{ f16(T(v,ty,u)) : ty=0..3 },
// T(v,ty,u) = sum_e embed[v,e]*W_ih[ty*50+u, e] + b_ih[g] + b_hh[g]  (u<50 else 0)
__global__ void build_T(const float* __restrict__ embed,
                        const float* __restrict__ Wih,
                        const float* __restrict__ bih,
                        const float* __restrict__ bhh,
                        ushort4* __restrict__ Tt) {
    int idx = blockIdx.x * blockDim.x + threadIdx.x;   // over 13*64
    if (idx >= VOC * UPAD) return;
    int v = idx >> 6, u = idx & 63;
    ushort4 r = {0, 0, 0, 0};
    if (u < HID) {
        ushort vals[4];
        for (int ty = 0; ty < 4; ++ty) {
            int g = ty * HID + u;
            float t = bih[g] + bhh[g];
            for (int e = 0; e < HID; ++e)
                t = fmaf(embed[v * HID + e], Wih[g * HID + e], t);
            vals[ty] = f16b(t);
        }
        r.x = vals[0]; r.y = vals[1]; r.z = vals[2]; r.w = vals[3];
    }
    Tt[idx] = r;
}

// 2048 blocks x 64 threads: ONE WAVE per batch element.
// No __syncthreads in the step loop (same-wave DS ops are in-order).
// No global loads in the step loop (tokens + T-table preloaded to LDS).
// A-rows replicated (all rows = h) -> C is row-independent -> all 64 lanes
// activate one unit each (u = lane), selecting tile j = q via cndmask.
__global__ __launch_bounds__(64, 2) void lstm_wave(
    const int*     __restrict__ x,
    const ushort*  __restrict__ Bmat,
    const ushort4* __restrict__ Ttg,
    const float*   __restrict__ W1,
    const float*   __restrict__ b1,
    const float*   __restrict__ W2,
    const float*   __restrict__ b2,
    float*         __restrict__ out)
{
    const int l   = threadIdx.x;    // lane = hidden unit u
    const int q   = l >> 4;
    const int c16 = l & 15;

    __shared__ __align__(16) ushort  hA[KPAD];          // h (f16), single buffer
    __shared__ __align__(16) int     xs[T_SEQ + 4];     // token stream (8 KB)
    __shared__ __align__(16) ushort4 Tl[VOC * UPAD];    // T-table (6.7 KB)

    // ---- B fragments: 32 frags, MFMA-only use -> AGPR-resident for free ----
    half8 bf[4][4][2];   // [ty][j][kf]
    #pragma unroll
    for (int ty = 0; ty < 4; ++ty)
        #pragma unroll
        for (int j = 0; j < 4; ++j)
            #pragma unroll
            for (int kf = 0; kf < 2; ++kf) {
                int n = ty * UPAD + j * 16 + c16;
                bf[ty][j][kf] = *(const half8*)(Bmat + n * KPAD + kf * 32 + q * 8);
            }

    // ---- preload tokens + T-table to LDS; init h ----
    {
        const int4* xg = (const int4*)(x + (long)blockIdx.x * T_SEQ);
        int4* xs4 = (int4*)xs;
        #pragma unroll
        for (int i = 0; i < T_SEQ / 4 / 64; ++i)       // 8 iterations
            xs4[l + i * 64] = xg[l + i * 64];
        for (int i = l; i < VOC * UPAD; i += 64)
            Tl[i] = Ttg[i];
        if (l == 0) { xs[T_SEQ] = 0; }
        hA[l] = 0;
    }
    __syncthreads();     // once, outside the loop

    f32x4 zc = {0.f, 0.f, 0.f, 0.f};                   // shared zero-C operand
    asm volatile("" : "+v"(zc));                       // hoist guard

    float c = 0.f;                                     // cell state for unit l
    int tok_cur = xs[0];

    for (int s = 0; s < T_SEQ; ++s) {
        // early LDS issues: T-row for this step, h fragments, next token
        ushort4 tv = Tl[tok_cur * UPAD + l];           // ds_read_b64
        half8 a0 = *(const half8*)(hA + q * 8);        // k 0..31  (broadcast x16)
        half8 a1 = *(const half8*)(hA + 32 + q * 8);   // k 32..63
        int tok_nxt = xs[s + 1];                       // uniform broadcast

        f32x4 z[4][4];
        #pragma unroll
        for (int ty = 0; ty < 4; ++ty)
            #pragma unroll
            for (int j = 0; j < 4; ++j) {
                f32x4 t0 = __builtin_amdgcn_mfma_f32_16x16x32_f16(a0, bf[ty][j][0], zc, 0, 0, 0);
                z[ty][j] = __builtin_amdgcn_mfma_f32_16x16x32_f16(a1, bf[ty][j][1], t0, 0, 0, 0);
            }

        // row-independent C (replicated A): pick tile j = q, reg 0
        float g4[4];
        #pragma unroll
        for (int ty = 0; ty < 4; ++ty) {
            float s01 = (q & 1) ? z[ty][1][0] : z[ty][0][0];
            float s23 = (q & 1) ? z[ty][3][0] : z[ty][2][0];
            g4[ty] = (q & 2) ? s23 : s01;
        }

        float iv = sigm(g4[0] + h2f(tv.x));
        float fv = sigm(g4[1] + h2f(tv.y));
        float gv = tanh_(g4[2] + h2f(tv.z));
        float ov = sigm(g4[3] + h2f(tv.w));
        c = fv * c + iv * gv;
        float h = ov * tanh_(c);                       // lanes u>=50: stays 0
        hA[l] = f16b(h);                               // ds_write_b16, in-order

        tok_cur = tok_nxt;
    }
    __syncthreads();

    // ---- epilogue MLP (once): lane u<50 computes relu(W1 h + b1)[u] ----
    float* Rf = (float*)xs;                            // reuse LDS
    if (l < HID) {
        float a = b1[l];
        #pragma unroll 10
        for (int k = 0; k < HID; ++k)
            a = fmaf(W1[l * HID + k], h2f(hA[k]), a);
        Rf[l] = fmaxf(a, 0.f);
    }
    __syncthreads();
    if (l == 0) {
        float a = b2[0];
        #pragma unroll 10
        for (int j = 0; j < HID; ++j)
            a = fmaf(W2[j], Rf[j], a);
        out[blockIdx.x] = a;
    }
}

extern "C" void kernel_launch(void* const* d_in, const int* in_sizes, int n_in,
                              void* d_out, int out_size, void* d_ws, size_t ws_size,
                              hipStream_t stream) {
    const int*   x     = (const int*)  d_in[0];
    const float* embed = (const float*)d_in[1];
    const float* W_ih  = (const float*)d_in[2];
    const float* W_hh  = (const float*)d_in[3];
    const float* b_ih  = (const float*)d_in[4];
    const float* b_hh  = (const float*)d_in[5];
    const float* W1    = (const float*)d_in[6];
    const float* b1    = (const float*)d_in[7];
    const float* W2    = (const float*)d_in[8];
    const float* b2    = (const float*)d_in[9];
    float* out = (float*)d_out;

    ushort*  Bmat = (ushort*)d_ws;                         // 32 KB
    ushort4* Ttg  = (ushort4*)((char*)d_ws + NPAD * KPAD * 2);  // 6.7 KB

    build_B<<<(NPAD * KPAD + 255) / 256, 256, 0, stream>>>(W_hh, Bmat);
    build_T<<<(VOC * UPAD + 255) / 256, 256, 0, stream>>>(embed, W_ih, b_ih, b_hh, Ttg);

    lstm_wave<<<NBLK, 64, 0, stream>>>(x, Bmat, Ttg, W1, b1, W2, b2, out);
}